// Round 12
// baseline (861.177 us; speedup 1.0000x reference)
//
#include <hip/hip_runtime.h>

typedef __attribute__((ext_vector_type(8))) short short8;
typedef __attribute__((ext_vector_type(4))) float f32x4;

__device__ __forceinline__ unsigned short f2bf(float f) {
  union { float f; unsigned u; } v; v.f = f;
  unsigned r = v.u + 0x7fffu + ((v.u >> 16) & 1u);
  return (unsigned short)(r >> 16);
}

__device__ __forceinline__ void async16(const void* g, void* l) {
  __builtin_amdgcn_global_load_lds(
      (const __attribute__((address_space(1))) unsigned*)g,
      (__attribute__((address_space(3))) unsigned*)l, 16, 0, 0);
}

#define MEMFENCE() asm volatile("" ::: "memory")
#define BARRIER() __builtin_amdgcn_s_barrier()
#define WAIT_VM(N) asm volatile("s_waitcnt vmcnt(" #N ")" ::: "memory")

// Exact-GELU via Abramowitz-Stegun 7.1.26 erf (|eps| <= 1.5e-7).
__device__ __forceinline__ float gelu_exact(float v) {
  float s = v * 0.70710678118f;
  float x = fabsf(s);
  float t = 1.0f / (1.0f + 0.3275911f * x);
  float p = t * (0.254829592f +
            t * (-0.284496736f +
            t * (1.421413741f + t * (-1.453152027f + t * 1.061405429f))));
  float er = 1.0f - p * __expf(-x * x);
  er = copysignf(er, s);
  return 0.5f * v * (1.0f + er);
}

// ---------------- fp32 -> bf16 bulk convert ----------------
__global__ void cvt_bf16_kernel(const float4* __restrict__ in,
                                ushort4* __restrict__ out, int n4) {
  int i = blockIdx.x * blockDim.x + threadIdx.x;
  int stride = gridDim.x * blockDim.x;
  for (; i < n4; i += stride) {
    float4 v = in[i];
    ushort4 o;
    o.x = f2bf(v.x); o.y = f2bf(v.y); o.z = f2bf(v.z); o.w = f2bf(v.w);
    out[i] = o;
  }
}

// ---------------- W_eff[e] = W + 2.0 * b[e] @ a[e], output bf16 ----------------
__global__ void make_weff(const float* __restrict__ w,
                          const float* __restrict__ bmat,
                          const float* __restrict__ amat,
                          unsigned short* __restrict__ out,
                          int J, int K) {
  const int e = blockIdx.y;
  const float* a = amat + (size_t)e * 64 * K;
  const float* b = bmat + (size_t)e * J * 64;
  const int j0 = blockIdx.x * 16;
  __shared__ float bs[16][64];
  const int tid = threadIdx.x;
  for (int i = tid; i < 16 * 64; i += 256)
    bs[i >> 6][i & 63] = b[(size_t)(j0 + (i >> 6)) * 64 + (i & 63)];
  __syncthreads();
  for (int k = tid; k < K; k += 256) {
    float acc[16];
#pragma unroll
    for (int jj = 0; jj < 16; ++jj) acc[jj] = 0.f;
    for (int r = 0; r < 64; ++r) {
      float av = a[(size_t)r * K + k];
#pragma unroll
      for (int jj = 0; jj < 16; ++jj) acc[jj] += bs[jj][r] * av;
    }
#pragma unroll
    for (int jj = 0; jj < 16; ++jj) {
      float v = w[(size_t)(j0 + jj) * K + k] + 2.0f * acc[jj];
      out[((size_t)e * J + j0 + jj) * K + k] = f2bf(v);
    }
  }
}

// ---------------- 256x128 grouped GEMM, pair-slot schedule --------------------
// Round-11 geometry (4 waves, wave 128x64, BK=32, triple-buf 72 KB, 2 blk/CU,
// slot s -> buf s%3, swizzle slot^((row>>1)&3)) with HALVED sync frequency:
// per pair {t,t+1}:
//   stage t+2 -> buf (t+2)%3      [freed by prev pair's mid-barrier]
//   read frags of BOTH slots (24 ds_read_b128, 96 VGPR)
//   lgkmcnt(0) + sched_barrier(0); BARRIER  [all waves' reads returned]
//   stage t+3 -> buf t%3          [WAR-safe: reads globally complete]
//   64 MFMA (32 per slot, same acc)
//   WAIT_VM(0)  [12 loads issued >=2400cy ago - no stall steady-state]
//   BARRIER
// Buffer cycle period = 3 pairs -> x3 static unroll (T % 6 == 0: 24, 96).
// Pair j in group: P0=(2j)%3, P1=(2j+1)%3, D2=(2j+2)%3, D3=P0;
// stage offsets GO2=(2j+2)*64B, GO3=GO2+64B; group advances ptrs by 384B.
// Last group's pair 2 stages tiles T,T+1 -> wrapped ptrs (garbage, never read).

#define PAIR(P0, P1, D2, GO2, sA0, sA1, sA2, sA3, sB0, sB1)                    \
  do {                                                                         \
    async16(sA0 + (GO2), ldsA + (D2) * 8192 + ldst);                           \
    async16(sA1 + (GO2), ldsA + (D2) * 8192 + 2048 + ldst);                    \
    async16(sA2 + (GO2), ldsA + (D2) * 8192 + 4096 + ldst);                    \
    async16(sA3 + (GO2), ldsA + (D2) * 8192 + 6144 + ldst);                    \
    async16(sB0 + (GO2), ldsB + (D2) * 4096 + ldst);                           \
    async16(sB1 + (GO2), ldsB + (D2) * 4096 + 2048 + ldst);                    \
    short8 af0[8], bf0[4], af1[8], bf1[4];                                     \
    _Pragma("unroll") for (int n_ = 0; n_ < 4; ++n_)                           \
        bf0[n_] = *(const short8*)(bRd + (P0) * 8192 + n_ * 1024);             \
    _Pragma("unroll") for (int m_ = 0; m_ < 8; ++m_)                           \
        af0[m_] = *(const short8*)(aRd + (P0) * 16384 + m_ * 1024);            \
    _Pragma("unroll") for (int n_ = 0; n_ < 4; ++n_)                           \
        bf1[n_] = *(const short8*)(bRd + (P1) * 8192 + n_ * 1024);             \
    _Pragma("unroll") for (int m_ = 0; m_ < 8; ++m_)                           \
        af1[m_] = *(const short8*)(aRd + (P1) * 16384 + m_ * 1024);            \
    asm volatile("s_waitcnt lgkmcnt(0)" ::: "memory");                         \
    __builtin_amdgcn_sched_barrier(0);                                         \
    BARRIER(); MEMFENCE();                                                     \
    async16(sA0 + (GO2) + 64, ldsA + (P0) * 8192 + ldst);                      \
    async16(sA1 + (GO2) + 64, ldsA + (P0) * 8192 + 2048 + ldst);               \
    async16(sA2 + (GO2) + 64, ldsA + (P0) * 8192 + 4096 + ldst);               \
    async16(sA3 + (GO2) + 64, ldsA + (P0) * 8192 + 6144 + ldst);               \
    async16(sB0 + (GO2) + 64, ldsB + (P0) * 4096 + ldst);                      \
    async16(sB1 + (GO2) + 64, ldsB + (P0) * 4096 + 2048 + ldst);               \
    __builtin_amdgcn_s_setprio(1);                                             \
    _Pragma("unroll") for (int m_ = 0; m_ < 8; ++m_)                           \
    _Pragma("unroll") for (int n_ = 0; n_ < 4; ++n_)                           \
        acc[m_][n_] = __builtin_amdgcn_mfma_f32_16x16x32_bf16(                 \
            af0[m_], bf0[n_], acc[m_][n_], 0, 0, 0);                           \
    _Pragma("unroll") for (int m_ = 0; m_ < 8; ++m_)                           \
    _Pragma("unroll") for (int n_ = 0; n_ < 4; ++n_)                           \
        acc[m_][n_] = __builtin_amdgcn_mfma_f32_16x16x32_bf16(                 \
            af1[m_], bf1[n_], acc[m_][n_], 0, 0, 0);                           \
    __builtin_amdgcn_s_setprio(0);                                             \
    WAIT_VM(0); MEMFENCE(); BARRIER(); MEMFENCE();                             \
  } while (0)

template <bool FUSE_GELU, bool OUT_BF16>
__global__ __launch_bounds__(256, 2) void gemm128(
    const unsigned short* __restrict__ A, const unsigned short* __restrict__ Bw,
    const float* __restrict__ bias, void* __restrict__ Cout, int N, int K,
    int NXT) {
  extern __shared__ unsigned short lds[];
  unsigned short* ldsA = lds;            // 3 x 8192 elems (16 KB)
  unsigned short* ldsB = lds + 24576;    // 3 x 4096 elems (8 KB)

  const int tid = threadIdx.x;           // 0..255
  const int w = tid >> 6, lane = tid & 63;

  // XCD-aware bijective swizzle (gridDim.x % 8 == 0 by construction)
  const int nwg = gridDim.x, bid = blockIdx.x;
  const int qchunk = nwg >> 3;
  const int wg = (bid & 7) * qchunk + (bid >> 3);
  const int by = wg / NXT, bx = wg - by * NXT;
  const int m0 = by << 8, n0 = bx << 7;
  const int e = (m0 % 1280) ? 1 : 0;  // 256-aligned tiles never span experts
  const unsigned short* Ap = A + (size_t)m0 * K;
  const unsigned short* Bp = Bw + ((size_t)e * N + n0) * K;

  const int wr = w >> 1, wc = w & 1;
  const int fr = lane & 15;
  const int cbv = (((lane >> 4) ^ ((fr >> 1) & 3)) << 4);  // swizzled slot
  const char* aRd = (const char*)lds + (wr * 128 + fr) * 64 + cbv;
  const char* bRd = (const char*)lds + 49152 + (wc * 64 + fr) * 64 + cbv;

  // staging: thread -> row tid>>2 (within 64-row panel), slot
  // (tid&3)^((tid>>3)&3); LDS dest linear (HW adds lane*16B).
  const int sslot = (tid & 3) ^ ((tid >> 3) & 3);
  const size_t grow = (size_t)(tid >> 2) * K * 2 + sslot * 16;
  const size_t KP = (size_t)K * 128;  // 64 rows of bytes
  const char* gA0 = (const char*)Ap + grow;
  const char* gA1 = gA0 + KP;
  const char* gA2 = gA0 + 2 * KP;
  const char* gA3 = gA0 + 3 * KP;
  const char* gB0 = (const char*)Bp + grow;
  const char* gB1 = gB0 + KP;
  const int ldst = w * 512;  // wave-uniform element base (HW adds lane*16B)

  f32x4 acc[8][4] = {};

  const int T = K >> 5;    // 32-wide K tiles (24 or 96; divisible by 6)
  const int G = T / 6;     // groups of 3 pairs
  const int KB2 = K << 1;  // bytes per row

  // ---- prologue: tile 0 -> buf0 (6 loads), tile 1 -> buf1 (6 loads) ----
  async16(gA0, ldsA + ldst);
  async16(gA1, ldsA + 2048 + ldst);
  async16(gA2, ldsA + 4096 + ldst);
  async16(gA3, ldsA + 6144 + ldst);
  async16(gB0, ldsB + ldst);
  async16(gB1, ldsB + 2048 + ldst);
  async16(gA0 + 64, ldsA + 8192 + ldst);
  async16(gA1 + 64, ldsA + 10240 + ldst);
  async16(gA2 + 64, ldsA + 12288 + ldst);
  async16(gA3 + 64, ldsA + 14336 + ldst);
  async16(gB0 + 64, ldsB + 4096 + ldst);
  async16(gB1 + 64, ldsB + 6144 + ldst);
  WAIT_VM(0); MEMFENCE(); BARRIER(); MEMFENCE();

  for (int g = 0; g < G - 1; ++g) {
    PAIR(0, 1, 2, 128, gA0, gA1, gA2, gA3, gB0, gB1);
    PAIR(2, 0, 1, 256, gA0, gA1, gA2, gA3, gB0, gB1);
    PAIR(1, 2, 0, 384, gA0, gA1, gA2, gA3, gB0, gB1);
    gA0 += 384; gA1 += 384; gA2 += 384; gA3 += 384; gB0 += 384; gB1 += 384;
  }
  {  // peeled last group: pair 2 stages tiles T, T+1 -> wrapped (never read)
    PAIR(0, 1, 2, 128, gA0, gA1, gA2, gA3, gB0, gB1);
    PAIR(2, 0, 1, 256, gA0, gA1, gA2, gA3, gB0, gB1);
    const char* wA0 = gA0 - KB2; const char* wA1 = gA1 - KB2;
    const char* wA2 = gA2 - KB2; const char* wA3 = gA3 - KB2;
    const char* wB0 = gB0 - KB2; const char* wB1 = gB1 - KB2;
    PAIR(1, 2, 0, 384, wA0, wA1, wA2, wA3, wB0, wB1);
  }

  // ---- epilogue: C/D layout col=lane&15, row=(lane>>4)*4+j ----
  const int lrow = (lane >> 4) << 2;
#pragma unroll
  for (int mi = 0; mi < 8; ++mi) {
    const int rbase = m0 + wr * 128 + mi * 16 + lrow;
#pragma unroll
    for (int n = 0; n < 4; ++n) {
      const int col = n0 + wc * 64 + n * 16 + fr;
      const float bv = bias[col];
#pragma unroll
      for (int j = 0; j < 4; ++j) {
        const int row = rbase + j;
        float v = acc[mi][n][j] + bv;
        if (FUSE_GELU) v = gelu_exact(v);
        if (OUT_BF16)
          ((unsigned short*)Cout)[(size_t)row * N + col] = f2bf(v);
        else
          ((float*)Cout)[(size_t)row * N + col] = v;
      }
    }
  }
}

extern "C" void kernel_launch(void* const* d_in, const int* in_sizes, int n_in,
                              void* d_out, int out_size, void* d_ws,
                              size_t ws_size, hipStream_t stream) {
  const float* x = (const float*)d_in[0];
  const float* w1 = (const float*)d_in[1];
  const float* bias1 = (const float*)d_in[2];
  const float* a1 = (const float*)d_in[3];
  const float* b1 = (const float*)d_in[4];
  const float* w2 = (const float*)d_in[5];
  const float* bias2 = (const float*)d_in[6];
  const float* a2 = (const float*)d_in[7];
  const float* b2 = (const float*)d_in[8];
  float* out = (float*)d_out;

  char* ws = (char*)d_ws;
  unsigned short* x_bf = (unsigned short*)(ws + 0);        // 40960*768 bf16
  unsigned short* w1e = (unsigned short*)(ws + 62914560);  // 2*3072*768 bf16
  unsigned short* w2e = (unsigned short*)(ws + 72351744);  // 2*768*3072 bf16
  unsigned short* h = (unsigned short*)(ws + 81788928);    // 40960*3072 bf16

  hipFuncSetAttribute(reinterpret_cast<const void*>(&gemm128<true, true>),
                      hipFuncAttributeMaxDynamicSharedMemorySize, 73728);
  hipFuncSetAttribute(reinterpret_cast<const void*>(&gemm128<false, false>),
                      hipFuncAttributeMaxDynamicSharedMemorySize, 73728);

  cvt_bf16_kernel<<<4096, 256, 0, stream>>>((const float4*)x, (ushort4*)x_bf,
                                            40960 * 768 / 4);
  make_weff<<<dim3(3072 / 16, 2), 256, 0, stream>>>(w1, b1, a1, w1e, 3072, 768);
  make_weff<<<dim3(768 / 16, 2), 256, 0, stream>>>(w2, b2, a2, w2e, 768, 3072);

  // M=40960 -> 160 M-tiles; GEMM1: 160x24=3840 wgs; GEMM2: 160x6=960 wgs
  gemm128<true, true><<<3840, 256, 73728, stream>>>(x_bf, w1e, bias1, h, 3072,
                                                    768, 24);
  gemm128<false, false><<<960, 256, 73728, stream>>>(h, w2e, bias2, out, 768,
                                                     3072, 6);
}